// Round 5
// baseline (164.374 us; speedup 1.0000x reference)
//
#include <hip/hip_runtime.h>
#include <hip/hip_bf16.h>
#include <hip/hip_fp8.h>
#include <stdint.h>

// Shapes: b=2, n=5, k=5, q=75, t=196, c=384, s=k*t=980 (padded to 1024/class)
// M per b = 75*196 = 14700 (58 tiles of 256 rows). Outputs: logits[750] ++ cls_logits[750].
// Sim branch: fp8-e4m3 MX-scaled MFMA (scales=1.0); cls branch exact fp32.
//
// Round-14: 32x32x64 MFMA + depth-6 register pipeline (no LDS, no barriers).
// R13 post-mortem: depth-3 16x16x128 lifted MfmaUtil 29->36% (latency theory right in
// direction), but per chunk the wave still issues 24 MFMA + 48 Bf-assembly movs and the
// prefetch window (~2.5 k-steps ~ 340cyc wall) is marginal vs loaded L2 latency.
// This round: mfma_scale_f32_32x32x64_f8f6f4 — same FLOPs & B traffic, but
//   (1) MFMA instruction count halves (12/chunk), fewer issue slots + chain links;
//   (2) K=64 slots are 2KB -> depth-6 pipeline in 48 regs, window ~5 k-steps (>~500cyc);
//   (3) fold-mask depends only on lane (col = sh*512+chunk*32+(lane&31)) -> one
//       wave-uniform branch for 30/32 chunks; sh=1 chunk 15 (all pad) skipped entirely.
// Fragment layouts follow the verified 16x16x128 pattern (lane holds contiguous 32-byte
// k-slice at (lane>>5)*32; C/D: col=lane&31, row=(reg&3)+8*(reg>>2)+4*(lane>>5)).
// Regs: A[2][6]=96 + SL/SH=48 + acc 32 + rmax 32 + addr ~16 ~= 224 -> 2 waves/SIMD.

typedef __attribute__((ext_vector_type(8))) int int8v;      // f8f6f4 A/B operand (32 fp8)
typedef __attribute__((ext_vector_type(16))) float f32x16;  // 32x32 MFMA C/D frag

__device__ __forceinline__ unsigned enc_f(float f) {
    unsigned b = __float_as_uint(f);
    return (b & 0x80000000u) ? ~b : (b | 0x80000000u);
}
__device__ __forceinline__ float dec_f(unsigned u) {
    unsigned b = (u & 0x80000000u) ? (u & 0x7FFFFFFFu) : ~u;
    return __uint_as_float(b);
}

__device__ __forceinline__ unsigned pack4_fp8(float a, float b, float c, float d) {
    int r = __builtin_amdgcn_cvt_pk_fp8_f32(a, b, 0, false);   // bytes 0,1
    r = __builtin_amdgcn_cvt_pk_fp8_f32(c, d, r, true);        // bytes 2,3
    return (unsigned)r;
}

// ---------------- fused prep: norm (16 lanes/row) | proto | init_P ----------------
// Query rows -> fqn row-major [tr][96 words]. Shot rows -> fsnp in 32x32x64 FRAGMENT
// order: per (bn,sh) slice of 49152 words, frag(chunk,ks6) is a 2048B block pair:
//   word = chunk*3072 + (2*ks6 + half)*256 + (kh*32 + (c&31))*4 + wb
// For a row (class-col c) and word j,l16 (k-bytes 64j+4*l16 .. +3):
//   ks6 = j, kh = l16>>3, half = (l16>>2)&1, wb = l16&3.
// gemm lane l then reads col (l&31), k-slice (l>>5)*32 via two coalesced 1KB loads.
__global__ void prep_kernel(const float* __restrict__ feat_query,
                            const float* __restrict__ feat_shot,
                            const float* __restrict__ x_shot,
                            unsigned* __restrict__ fqn,
                            unsigned* __restrict__ fsnp,
                            float* __restrict__ proto,
                            unsigned* __restrict__ P) {
    const int blk  = blockIdx.x;
    const int tid  = threadIdx.x;
    const int lane = tid & 63;
    const int wv   = tid >> 6;

    if (blk < 2478) {                       // ---- token L2 norm -> fp8, 4 rows/wave ----
        const int tr  = blk * 16 + wv * 4 + (lane >> 4);   // 0..39639
        const int l16 = lane & 15;
        if (tr >= 39640) return;

        const float* row;
        unsigned* o32;
        bool zero = false;
        bool shot = false;
        if (tr < 29400) {
            row = feat_query + (size_t)tr * 384;
            o32 = fqn + (size_t)tr * 96;
        } else {
            const int sp = tr - 29400;          // padded shot row: [bn][1024]
            const int bn = sp >> 10;
            const int s  = sp & 1023;           // col within class block
            row  = feat_shot + ((size_t)bn * 980 + s) * 384;
            zero = (s >= 980);
            shot = true;
            const int shh   = s >> 9;
            const int c9    = s & 511;
            const int chunk = c9 >> 5;
            o32 = fsnp + (size_t)bn * 98304 + shh * 49152 + chunk * 3072
                       + ((l16 >> 3) * 32 + (c9 & 31)) * 4 + (l16 & 3);
        }
        // per-j store index (fragment order for shot, row-major for query)
        int idxs[6];
#pragma unroll
        for (int j = 0; j < 6; ++j)
            idxs[j] = shot ? ((2 * j + ((l16 >> 2) & 1)) * 256)
                           : (l16 + 16 * j);

        if (zero) {
#pragma unroll
            for (int j = 0; j < 6; ++j) o32[idxs[j]] = 0u;
            return;
        }
        const float4* rf4 = (const float4*)row;
        float4 v[6];
        float ss = 0.f;
#pragma unroll
        for (int j = 0; j < 6; ++j) {
            v[j] = rf4[l16 + 16 * j];
            ss += v[j].x * v[j].x + v[j].y * v[j].y + v[j].z * v[j].z + v[j].w * v[j].w;
        }
#pragma unroll
        for (int off = 1; off < 16; off <<= 1) ss += __shfl_xor(ss, off, 64);
        const float sc = 1.0f / fmaxf(sqrtf(ss), 1e-8f);
#pragma unroll
        for (int j = 0; j < 6; ++j)
            o32[idxs[j]] = pack4_fp8(v[j].x * sc, v[j].y * sc, v[j].z * sc, v[j].w * sc);
    } else if (blk < 2481) {                // ---- proto = l2norm(mean_k x_shot), fp32 ----
        const int gw = (blk - 2478) * 4 + wv;
        if (gw >= 10) return;
        const float* base = x_shot + (size_t)gw * 5 * 384;
        float v[6];
        float ss = 0.f;
#pragma unroll
        for (int j = 0; j < 6; ++j) {
            float s = 0.f;
#pragma unroll
            for (int kk = 0; kk < 5; ++kk) s += base[kk * 384 + lane + 64 * j];
            s *= 0.2f;
            v[j] = s;
            ss += s * s;
        }
#pragma unroll
        for (int off = 1; off < 64; off <<= 1) ss += __shfl_xor(ss, off, 64);
        const float scale = 1.0f / fmaxf(sqrtf(ss), 1e-12f);
#pragma unroll
        for (int j = 0; j < 6; ++j) proto[(size_t)gw * 384 + lane + 64 * j] = v[j] * scale;
    } else {                                // ---- init P to encoded -inf (0) ----
        const int i = (blk - 2481) * 256 + tid;
        if (i < 147000) P[i] = 0u;
    }
}

// ---------------- fp8 GEMM + row-max: 256 A-rows in regs, B depth-6 pipelined ----------------
// grid = 2b x 5cls x 2sh x 58mt = 1160 blocks; 256 thr = 4 waves (64 rows each, 2 tiles
// of 32). No LDS, no barriers. B streams from the fragment-ordered fsnp: per K=64 step,
// 2 coalesced 1KB dwordx4 loads feeding 2 MFMAs (mi=0,1); rolling 6-slot register
// pipeline (slot ks6 reissued for the NEXT chunk right after its MFMAs -> issue->use
// window = 5 k-steps, > loaded L2 latency). sh=1 chunk 15 (cols 992..1023, all pad)
// is skipped entirely.
__global__ __launch_bounds__(256, 2) void gemm_kernel(const uint8_t* __restrict__ fqn,
                                                      const uint8_t* __restrict__ fsnp,
                                                      unsigned* __restrict__ P) {
    const int bid = blockIdx.x;       // (((b*5+cls)*2)+sh)*58 + mt
    const int mt  = bid % 58;
    const int g1  = bid / 58;
    const int sh  = g1 & 1;
    const int bc  = g1 >> 1;          // b*5+cls
    const int b   = bc / 5;
    const int m0  = mt * 256;

    const int tid  = threadIdx.x;
    const int lane = tid & 63;
    const int wv   = tid >> 6;
    const int l31  = lane & 31;
    const int kh   = lane >> 5;       // which 32-byte k-half of the 64-wide k-step

    const uint8_t* Ag = fqn  + (size_t)b * 14700 * 384;
    const uint8_t* Bg = fsnp + (size_t)bc * 393216 + (size_t)sh * 196608;
    const uint8_t* bp = Bg + lane * 16;    // + chunk*12288 + ks6*2048 (+1024 for hi)

    // ---- A fragments -> registers (one-time; wave wv holds rows m0+wv*64 .. +63) ----
    int8v A[2][6];
#pragma unroll
    for (int mi = 0; mi < 2; ++mi) {
        int row = m0 + wv * 64 + mi * 32 + l31;
        row = row < 14700 ? row : 14699;           // clamp; dead rows masked at epilogue
        const uint8_t* pa = Ag + (size_t)row * 384 + kh * 32;
#pragma unroll
        for (int ks = 0; ks < 6; ++ks) {
            const uint4 x = *(const uint4*)(pa + ks * 64);
            const uint4 y = *(const uint4*)(pa + ks * 64 + 16);
            A[mi][ks] = (int8v){(int)x.x, (int)x.y, (int)x.z, (int)x.w,
                                (int)y.x, (int)y.y, (int)y.z, (int)y.w};
        }
    }

    float rmax[2][16];
#pragma unroll
    for (int mi = 0; mi < 2; ++mi)
#pragma unroll
        for (int i = 0; i < 16; ++i) rmax[mi][i] = -3.0e38f;

    // ---- prologue: fill the 6-slot pipeline with chunk 0's k-steps ----
    uint4 SL[6], SH[6];                     // statically indexed only
#pragma unroll
    for (int ks = 0; ks < 6; ++ks) {
        const uint8_t* p = bp + ks * 2048;
        SL[ks] = *(const uint4*)(p);
        SH[ks] = *(const uint4*)(p + 1024);
    }

    const int nchunk = (sh == 1) ? 15 : 16;     // sh=1 chunk 15 is 100% padding

    for (int chunk = 0; chunk < nchunk; ++chunk) {
        f32x16 acc0 = (f32x16)(0.f), acc1 = (f32x16)(0.f);
        const size_t nb = (size_t)((chunk + 1 < nchunk) ? chunk + 1 : chunk) * 12288;

#pragma unroll
        for (int ks = 0; ks < 6; ++ks) {
            const int8v Bf = (int8v){(int)SL[ks].x, (int)SL[ks].y,
                                     (int)SL[ks].z, (int)SL[ks].w,
                                     (int)SH[ks].x, (int)SH[ks].y,
                                     (int)SH[ks].z, (int)SH[ks].w};
            acc0 = __builtin_amdgcn_mfma_scale_f32_32x32x64_f8f6f4(
                A[0][ks], Bf, acc0, 0, 0, 0, 0x7F7F7F7F, 0, 0x7F7F7F7F);
            acc1 = __builtin_amdgcn_mfma_scale_f32_32x32x64_f8f6f4(
                A[1][ks], Bf, acc1, 0, 0, 0, 0x7F7F7F7F, 0, 0x7F7F7F7F);
            // re-issue slot ks for the next chunk (issue->use window = 5 k-steps)
            const uint8_t* p = bp + nb + ks * 2048;
            SL[ks] = *(const uint4*)(p);
            SH[ks] = *(const uint4*)(p + 1024);
        }

        // fold row-max; col = sh*512 + chunk*32 + l31 identical for all 16 regs.
        // sh=0: always valid. sh=1: chunks 0..13 fully valid, chunk 14 valid iff l31<20.
        if (sh == 0 || chunk < 14) {
#pragma unroll
            for (int i = 0; i < 16; ++i) {
                rmax[0][i] = fmaxf(rmax[0][i], acc0[i]);
                rmax[1][i] = fmaxf(rmax[1][i], acc1[i]);
            }
        } else if (chunk == 14) {
            if (l31 < 20) {
#pragma unroll
                for (int i = 0; i < 16; ++i) {
                    rmax[0][i] = fmaxf(rmax[0][i], acc0[i]);
                    rmax[1][i] = fmaxf(rmax[1][i], acc1[i]);
                }
            }
        }
    }

    // ---- epilogue: max over 32 col-lanes (within each 32-half), then atomicMax ----
    // C/D layout: col = lane&31, row = (i&3) + 8*(i>>2) + 4*kh.
#pragma unroll
    for (int mi = 0; mi < 2; ++mi)
#pragma unroll
        for (int i = 0; i < 16; ++i) {
            float v = rmax[mi][i];
#pragma unroll
            for (int off = 1; off < 32; off <<= 1) v = fmaxf(v, __shfl_xor(v, off, 64));
            if (l31 == 0) {
                const int row = m0 + wv * 64 + mi * 32 + (i & 3) + 8 * (i >> 2) + 4 * kh;
                if (row < 14700)
                    atomicMax(&P[(size_t)bc * 14700 + row], enc_f(v));
            }
        }
}

// ---------------- fused final: logits (mean over t of row maxima) | cls_logits ----------------
__global__ void final_kernel(const unsigned* __restrict__ P,
                             const float* __restrict__ xq,
                             const float* __restrict__ proto,
                             float* __restrict__ out) {
    const int blk  = blockIdx.x;
    const int tid  = threadIdx.x;
    const int lane = tid & 63;
    const int wv   = tid >> 6;

    if (blk < 188) {                        // ---- logits ----
        const int gw = blk * 4 + wv;        // (b*75+q)*5+n
        if (gw >= 750) return;
        const int n  = gw % 5;
        const int bq = gw / 5;
        const int b  = bq / 75;
        const int q  = bq % 75;
        const unsigned* row = P + (size_t)(b * 5 + n) * 14700 + q * 196;
        float s = 0.f;
        for (int t = lane; t < 196; t += 64) s += dec_f(row[t]);
#pragma unroll
        for (int off = 1; off < 64; off <<= 1) s += __shfl_xor(s, off, 64);
        if (lane == 0) out[gw] = s * (1.0f / 196.0f);
    } else {                                // ---- cls_logits ----
        const int gw = (blk - 188) * 4 + wv;   // b*75+q
        if (gw >= 150) return;
        const float* row = xq + (size_t)gw * 384;
        float u[6];
        float ss = 0.f;
#pragma unroll
        for (int j = 0; j < 6; ++j) { u[j] = row[lane + 64 * j]; ss += u[j] * u[j]; }
#pragma unroll
        for (int off = 1; off < 64; off <<= 1) ss += __shfl_xor(ss, off, 64);
        const float scale = 1.0f / fmaxf(sqrtf(ss), 1e-12f);
#pragma unroll
        for (int j = 0; j < 6; ++j) u[j] *= scale;
        const int b = gw / 75;
        for (int n = 0; n < 5; ++n) {
            const float* p = proto + (size_t)(b * 5 + n) * 384;
            float d = 0.f;
#pragma unroll
            for (int j = 0; j < 6; ++j) d += u[j] * p[lane + 64 * j];
#pragma unroll
            for (int off = 1; off < 64; off <<= 1) d += __shfl_xor(d, off, 64);
            if (lane == 0) out[750 + gw * 5 + n] = 10.0f * d;
        }
    }
}

extern "C" void kernel_launch(void* const* d_in, const int* in_sizes, int n_in,
                              void* d_out, int out_size, void* d_ws, size_t ws_size,
                              hipStream_t stream) {
    const float* feat_shot  = (const float*)d_in[0];  // [2,5,5,196,384]
    const float* feat_query = (const float*)d_in[1];  // [2,75,196,384]
    const float* x_shot     = (const float*)d_in[2];  // [2,5,5,384]
    const float* x_query    = (const float*)d_in[3];  // [2,75,384]
    float* out = (float*)d_out;
    char* ws = (char*)d_ws;

    // ws layout (15.8 MiB total)
    uint8_t*  fqn   = (uint8_t*)ws;                     // 29400*384  = 11,289,600 B (fp8, row-major)
    uint8_t*  fsnp  = (uint8_t*)(ws + 11289600);        // 10240*384  =  3,932,160 B (fp8, FRAGMENT order)
    float*    proto = (float*)(ws + 15221760);          //      3,840 f32
    unsigned* P     = (unsigned*)(ws + 15237120);       //    147,000 u32

    prep_kernel<<<3056, 256, 0, stream>>>(feat_query, feat_shot, x_shot,
                                          (unsigned*)fqn, (unsigned*)fsnp, proto, P);
    gemm_kernel<<<1160, 256, 0, stream>>>(fqn, fsnp, P);
    final_kernel<<<226, 256, 0, stream>>>(P, x_query, proto, out);
}